// Round 9
// baseline (81.089 us; speedup 1.0000x reference)
//
#include <hip/hip_runtime.h>

#define BB 16
#define CC 80
#define HWs 16384           // H*W
#define KK 100
#define NBIN 2048           // histogram bins = okey(logit) >> 21
#define SCAP 2048           // per-batch survivor capacity (~500-800 expected)
#define LCAP 256            // per-block survivor LDS capacity (mean ~5)

// ws layout (bytes)
#define OFF_BHIST 0                          // 16*2048*4 = 131072
#define OFF_CUT   131072                     // 64
#define OFF_SCNT  131136                     // 64
#define OFF_SURV  131200                     // 16*2048*4 = 131072 (end ~262KB)

__device__ __forceinline__ unsigned okey(float f) {
    unsigned u = __float_as_uint(f);
    return (u & 0x80000000u) ? ~u : (u | 0x80000000u);
}

// zero bhist (128 KB) + scnt
__global__ __launch_bounds__(256) void zero_kernel(int4* __restrict__ bhist,
                                                   int* __restrict__ scnt) {
    int i = blockIdx.x * 256 + threadIdx.x;          // 8192 int4 total
    if (i < BB * NBIN / 4) bhist[i] = make_int4(0, 0, 0, 0);
    if (blockIdx.x == 0 && threadIdx.x < BB) scnt[threadIdx.x] = 0;
}

// One block per half-plane (2560 blocks, ~100% occupancy). Pure streaming
// 3x3 stencil on raw logits (monotone w.r.t. sigmoid): peak -> LDS hist
// atomic. NO records, NO scans, NO mid-kernel barriers.
__global__ __launch_bounds__(256) void hist_kernel(const float* __restrict__ hm,
                                                   int* __restrict__ bhist) {
    __shared__ int hist[NBIN];             // 8 KB
    const int blk = blockIdx.x;            // plane*2 + half
    const int plane = blk >> 1;
    const int half = blk & 1;
    const int b = plane / CC;
    const int t = threadIdx.x;
    const int sx = t & 31;                 // 4-wide column strip
    const int base = (half << 6) + ((t >> 5) << 3);  // 8 bands x 8 rows
    const float4* __restrict__ src4 =
        reinterpret_cast<const float4*>(hm + (size_t)plane * HWs);

    for (int i = t; i < NBIN; i += 256) hist[i] = 0;
    __syncthreads();

    auto hmax3 = [&](const float4& a) -> float4 {
        float vm1 = __shfl_up(a.w, 1, 32);
        float vp4 = __shfl_down(a.x, 1, 32);
        if (sx == 0) vm1 = a.x;            // SAME padding (self-dup neutral)
        if (sx == 31) vp4 = a.w;
        float4 h;
        h.x = fmaxf(fmaxf(vm1, a.x), a.y);
        h.y = fmaxf(fmaxf(a.x, a.y), a.z);
        h.z = fmaxf(fmaxf(a.y, a.z), a.w);
        h.w = fmaxf(fmaxf(a.z, a.w), vp4);
        return h;
    };

#pragma unroll
    for (int chunk = 0; chunk < 2; ++chunk) {
        const int y0 = base + (chunk << 2);
        float4 v[6];
#pragma unroll
        for (int r = 0; r < 6; ++r) {
            int rr = y0 - 1 + r;
            rr = rr < 0 ? 0 : (rr > 127 ? 127 : rr);
            v[r] = src4[(rr << 5) + sx];
        }
        float4 hm1 = hmax3(v[0]);
        float4 h0  = hmax3(v[1]);
#pragma unroll
        for (int r = 0; r < 4; ++r) {
            float4 hp1 = hmax3(v[r + 2]);
            if (v[r + 1].x >= fmaxf(fmaxf(hm1.x, h0.x), hp1.x))
                atomicAdd(&hist[okey(v[r + 1].x) >> 21], 1);
            if (v[r + 1].y >= fmaxf(fmaxf(hm1.y, h0.y), hp1.y))
                atomicAdd(&hist[okey(v[r + 1].y) >> 21], 1);
            if (v[r + 1].z >= fmaxf(fmaxf(hm1.z, h0.z), hp1.z))
                atomicAdd(&hist[okey(v[r + 1].z) >> 21], 1);
            if (v[r + 1].w >= fmaxf(fmaxf(hm1.w, h0.w), hp1.w))
                atomicAdd(&hist[okey(v[r + 1].w) >> 21], 1);
            hm1 = h0; h0 = hp1;
        }
    }

    __syncthreads();
    for (int i = t; i < NBIN; i += 256) {
        int hv = hist[i];
        if (hv) atomicAdd(&bhist[b * NBIN + i], hv);   // fire-and-forget
    }
}

// One block per batch: cutoff = largest bin with suffix count >= K
// (superset of the exact sigmoid-top-100 incl. tie groups).
__global__ __launch_bounds__(256) void cut_kernel(const int* __restrict__ bhist,
                                                  int* __restrict__ cut) {
    __shared__ int csum[256];
    __shared__ int s_cut;
    const int b = blockIdx.x;
    const int t = threadIdx.x;

    int h[8]; int chunk = 0;
#pragma unroll
    for (int j = 0; j < 8; ++j) {
        h[j] = bhist[b * NBIN + (t << 3) + j];
        chunk += h[j];
    }
    csum[t] = chunk;
    if (t == 0) s_cut = 0;
    __syncthreads();
    for (int off = 1; off < 256; off <<= 1) {
        int v = (t + off < 256) ? csum[t + off] : 0;
        __syncthreads();
        csum[t] += v;
        __syncthreads();
    }
    if (csum[0] > KK) {
        int running = (t < 255) ? csum[t + 1] : 0;
        if (csum[t] >= KK && running < KK) {   // exactly one thread
            for (int j = 7; j >= 0; --j) {
                running += h[j];
                if (running >= KK) { s_cut = (t << 3) + j; break; }
            }
        }
    }
    __syncthreads();
    if (t == 0) cut[b] = s_cut;
}

// One block per half-plane: recompute stencil (L3-hot), emit peaks with
// bin >= cut[b] via LDS compaction; ONE returning global atomic per
// nonempty block (a few hundred total).
__global__ __launch_bounds__(256) void filter_kernel(const float* __restrict__ hm,
                                                     const int* __restrict__ cut,
                                                     unsigned* __restrict__ surv,
                                                     int* __restrict__ scnt) {
    __shared__ unsigned sbuf[LCAP];
    __shared__ int s_n, s_base;
    const int blk = blockIdx.x;            // plane*2 + half
    const int plane = blk >> 1;
    const int half = blk & 1;
    const int b = plane / CC;
    const int c = plane - b * CC;
    const int t = threadIdx.x;
    const int sx = t & 31;
    const int x0 = sx << 2;
    const int base = (half << 6) + ((t >> 5) << 3);
    const float4* __restrict__ src4 =
        reinterpret_cast<const float4*>(hm + (size_t)plane * HWs);
    const unsigned cutb = (unsigned)cut[b];

    if (t == 0) s_n = 0;
    __syncthreads();

    auto hmax3 = [&](const float4& a) -> float4 {
        float vm1 = __shfl_up(a.w, 1, 32);
        float vp4 = __shfl_down(a.x, 1, 32);
        if (sx == 0) vm1 = a.x;
        if (sx == 31) vp4 = a.w;
        float4 h;
        h.x = fmaxf(fmaxf(vm1, a.x), a.y);
        h.y = fmaxf(fmaxf(a.x, a.y), a.z);
        h.z = fmaxf(fmaxf(a.y, a.z), a.w);
        h.w = fmaxf(fmaxf(a.z, a.w), vp4);
        return h;
    };

#pragma unroll
    for (int chunk = 0; chunk < 2; ++chunk) {
        const int y0 = base + (chunk << 2);
        float4 v[6];
#pragma unroll
        for (int r = 0; r < 6; ++r) {
            int rr = y0 - 1 + r;
            rr = rr < 0 ? 0 : (rr > 127 ? 127 : rr);
            v[r] = src4[(rr << 5) + sx];
        }
        float4 hm1 = hmax3(v[0]);
        float4 h0  = hmax3(v[1]);
#pragma unroll
        for (int r = 0; r < 4; ++r) {
            float4 hp1 = hmax3(v[r + 2]);
            float vv[4] = { v[r + 1].x, v[r + 1].y, v[r + 1].z, v[r + 1].w };
            float mm[4] = { fmaxf(fmaxf(hm1.x, h0.x), hp1.x),
                            fmaxf(fmaxf(hm1.y, h0.y), hp1.y),
                            fmaxf(fmaxf(hm1.z, h0.z), hp1.z),
                            fmaxf(fmaxf(hm1.w, h0.w), hp1.w) };
#pragma unroll
            for (int j = 0; j < 4; ++j) {
                if (vv[j] >= mm[j] && (okey(vv[j]) >> 21) >= cutb) {
                    int sl = atomicAdd(&s_n, 1);       // LDS atomic: rare, cheap
                    unsigned idx = ((unsigned)c << 14)
                                 | ((unsigned)(y0 + r) << 7) | (unsigned)(x0 + j);
                    if (sl < LCAP) sbuf[sl] = idx;
                }
            }
            hm1 = h0; h0 = hp1;
        }
    }
    __syncthreads();
    int n = s_n; if (n > LCAP) n = LCAP;
    if (n == 0) return;
    if (t == 0) s_base = atomicAdd(&scnt[b], n);       // one per nonempty block
    __syncthreads();
    const int sb = s_base;
    for (int k = t; k < n; k += 256)
        if (sb + k < SCAP) surv[b * SCAP + sb + k] = sbuf[k];
}

// One block per batch: gather survivors, exact logit -> sigmoid, sort by
// (sigmoid_bits desc, idx asc) == lax.top_k tie semantics, gather + emit.
__global__ __launch_bounds__(256) void topk_kernel(const unsigned* __restrict__ surv,
                                                   const int* __restrict__ scnt,
                                                   const float* __restrict__ hm,
                                                   const float* __restrict__ bbox,
                                                   const float* __restrict__ offs,
                                                   const int* __restrict__ image_id,
                                                   float* __restrict__ out) {
    __shared__ unsigned long long list[SCAP];  // 16 KB
    const int b = blockIdx.x;
    const int t = threadIdx.x;
    int n = scnt[b]; if (n > SCAP) n = SCAP;
    const float* __restrict__ hb = hm + (size_t)b * CC * HWs;

    for (int i = t; i < n; i += 256) {
        unsigned idx = surv[b * SCAP + i];
        float lv = hb[idx];
        float s = 1.0f / (1.0f + expf(-lv));
        list[i] = ((unsigned long long)__float_as_uint(s) << 32) | (unsigned)(~idx);
    }
    int P = 128;
    while (P < n) P <<= 1;
    for (int i = n + t; i < P; i += 256) list[i] = 0ull;
    __syncthreads();

    for (int ksz = 2; ksz <= P; ksz <<= 1) {
        for (int j = ksz >> 1; j > 0; j >>= 1) {
            for (int i = t; i < P; i += 256) {
                int ixj = i ^ j;
                if (ixj > i) {
                    unsigned long long a = list[i], bb2 = list[ixj];
                    bool desc = ((i & ksz) == 0);
                    if (desc ? (a < bb2) : (a > bb2)) { list[i] = bb2; list[ixj] = a; }
                }
            }
            __syncthreads();
        }
    }

    if (t < KK) {
        float s = 0.0f; unsigned idx = 0;
        if (t < n) {
            unsigned long long cv = list[t];
            s = __uint_as_float((unsigned)(cv >> 32));
            idx = ~(unsigned)(cv & 0xFFFFFFFFu) & 0x1FFFFFu;
        }
        unsigned sp = idx & (HWs - 1);
        float cls = (float)(idx >> 14);
        float ysf = (float)(sp >> 7);
        float xsf = (float)(sp & 127);
        const float* __restrict__ ob  = offs + (size_t)b * 2 * HWs;
        const float* __restrict__ bbx = bbox + (size_t)b * 2 * HWs;
        float cx = xsf + ob[sp];
        float cy = ysf + ob[HWs + sp];
        float w = bbx[sp];
        float h = bbx[HWs + sp];
        float* row = out + ((size_t)b * KK + t) * 7;
        row[0] = (float)image_id[b];
        row[1] = (cx - w * 0.5f) * 4.0f;
        row[2] = (cy - h * 0.5f) * 4.0f;
        row[3] = (cx + w * 0.5f) * 4.0f;
        row[4] = (cy + h * 0.5f) * 4.0f;
        row[5] = s;
        row[6] = cls;
    }
}

extern "C" void kernel_launch(void* const* d_in, const int* in_sizes, int n_in,
                              void* d_out, int out_size, void* d_ws, size_t ws_size,
                              hipStream_t stream) {
    const float* hm      = (const float*)d_in[0];
    const float* bbox    = (const float*)d_in[1];
    const float* offset  = (const float*)d_in[2];
    const int*   img_id  = (const int*)d_in[3];
    float* out = (float*)d_out;

    char* ws = (char*)d_ws;
    int*      bhist = (int*)(ws + OFF_BHIST);
    int*      cut   = (int*)(ws + OFF_CUT);
    int*      scnt  = (int*)(ws + OFF_SCNT);
    unsigned* surv  = (unsigned*)(ws + OFF_SURV);

    zero_kernel<<<32, 256, 0, stream>>>((int4*)bhist, scnt);
    hist_kernel<<<BB * CC * 2, 256, 0, stream>>>(hm, bhist);
    cut_kernel<<<BB, 256, 0, stream>>>(bhist, cut);
    filter_kernel<<<BB * CC * 2, 256, 0, stream>>>(hm, cut, surv, scnt);
    topk_kernel<<<BB, 256, 0, stream>>>(surv, scnt, hm, bbox, offset, img_id, out);
}

// Round 10
// 80.514 us; speedup vs baseline: 1.0071x; 1.0071x over previous
//
#include <hip/hip_runtime.h>

#define BB 16
#define CC 80
#define HWs 16384           // H*W
#define KK 100
#define NBIN 2048           // histogram bins = okey(logit) >> 21
#define NBLK (BB * CC * 2)  // 2560 half-plane blocks
#define BCAP 1536           // records per half-plane block (mean ~910)
#define LCAP 128            // filter per-block survivor cap (mean ~5)
#define SCAP 2048           // per-batch survivor capacity (~500-800 expected)

// ws layout (bytes)
#define OFF_BHIST 0                          // 16*2048*4 = 131072
#define OFF_CUT   131072                     // 64
#define OFF_SCNT  131136                     // 64
#define OFF_PBCNT 131200                     // 2560*4 = 10240
#define OFF_SURV  141440                     // 16*2048*4 = 131072
#define OFF_REC   272512                     // 2560*1536*4 = 15.7 MB

__device__ __forceinline__ unsigned okey(float f) {
    unsigned u = __float_as_uint(f);
    return (u & 0x80000000u) ? ~u : (u | 0x80000000u);
}

// zero bhist (128 KB) + scnt
__global__ __launch_bounds__(256) void zero_kernel(int4* __restrict__ bhist,
                                                   int* __restrict__ scnt) {
    int i = blockIdx.x * 256 + threadIdx.x;          // 8192 int4 total
    if (i < BB * NBIN / 4) bhist[i] = make_int4(0, 0, 0, 0);
    if (blockIdx.x == 0 && threadIdx.x < BB) scnt[threadIdx.x] = 0;
}

// One block per half-plane (2560 blocks). Thread = 4col x 8row strip; ALL 10
// window rows loaded up front (deep MLP, 1.25x halo). Peaks -> LDS record
// buffer via LDS atomic (no scans, no mid-kernel barriers). Block hist is
// rebuilt from records at the end (hot loop has ONE LDS atomic per peak).
__global__ __launch_bounds__(256) void nms_kernel(const float* __restrict__ hm,
                                                  unsigned* __restrict__ rec,
                                                  int* __restrict__ pbcnt,
                                                  int* __restrict__ bhist) {
    __shared__ int hist[NBIN];             // 8 KB
    __shared__ unsigned sbuf[BCAP];        // 6 KB
    __shared__ int s_n;
    const int blk = blockIdx.x;            // plane*2 + half
    const int plane = blk >> 1;
    const int half = blk & 1;
    const int b = plane / CC;
    const int c = plane - b * CC;
    const int t = threadIdx.x;
    const int sx = t & 31;                 // 4-wide column strip
    const int x0 = sx << 2;
    const int y0 = (half << 6) + ((t >> 5) << 3);    // 8 bands x 8 rows
    const float4* __restrict__ src4 =
        reinterpret_cast<const float4*>(hm + (size_t)plane * HWs);

    for (int i = t; i < NBIN; i += 256) hist[i] = 0;
    if (t == 0) s_n = 0;
    __syncthreads();

    // all 10 window rows (y0-1 .. y0+8, clamped) issued before any compute
    float4 w[10];
#pragma unroll
    for (int i = 0; i < 10; ++i) {
        int rr = y0 - 1 + i;
        rr = rr < 0 ? 0 : (rr > 127 ? 127 : rr);
        w[i] = src4[(rr << 5) + sx];
    }

    auto hmax3 = [&](const float4& a) -> float4 {
        float vm1 = __shfl_up(a.w, 1, 32);
        float vp4 = __shfl_down(a.x, 1, 32);
        if (sx == 0) vm1 = a.x;            // SAME padding (self-dup neutral)
        if (sx == 31) vp4 = a.w;
        float4 h;
        h.x = fmaxf(fmaxf(vm1, a.x), a.y);
        h.y = fmaxf(fmaxf(a.x, a.y), a.z);
        h.z = fmaxf(fmaxf(a.y, a.z), a.w);
        h.w = fmaxf(fmaxf(a.z, a.w), vp4);
        return h;
    };

    float4 hm1 = hmax3(w[0]);
    float4 h0  = hmax3(w[1]);
#pragma unroll
    for (int r = 0; r < 8; ++r) {
        float4 hp1 = hmax3(w[r + 2]);
        float vv[4] = { w[r + 1].x, w[r + 1].y, w[r + 1].z, w[r + 1].w };
        float mm[4] = { fmaxf(fmaxf(hm1.x, h0.x), hp1.x),
                        fmaxf(fmaxf(hm1.y, h0.y), hp1.y),
                        fmaxf(fmaxf(hm1.z, h0.z), hp1.z),
                        fmaxf(fmaxf(hm1.w, h0.w), hp1.w) };
#pragma unroll
        for (int j = 0; j < 4; ++j) {
            if (vv[j] >= mm[j]) {          // peak (max-of-9 incl. self)
                int sl = atomicAdd(&s_n, 1);           // LDS atomic: cheap
                unsigned bin = okey(vv[j]) >> 21;
                unsigned idx = ((unsigned)c << 14)
                             | ((unsigned)(y0 + r) << 7) | (unsigned)(x0 + j);
                if (sl < BCAP) sbuf[sl] = (bin << 21) | idx;
            }
        }
        hm1 = h0; h0 = hp1;
    }
    __syncthreads();
    int n = s_n; if (n > BCAP) n = BCAP;

    // rebuild hist from records (amortized; ~4 records/thread)
    for (int i = t; i < n; i += 256) atomicAdd(&hist[sbuf[i] >> 21], 1);
    __syncthreads();

    for (int i = t; i < NBIN; i += 256) {
        int hv = hist[i];
        if (hv) atomicAdd(&bhist[b * NBIN + i], hv);   // fire-and-forget
    }
    unsigned* __restrict__ rb = rec + (size_t)blk * BCAP;
    for (int i = t; i < n; i += 256) rb[i] = sbuf[i];  // coalesced writeback
    if (t == 0) pbcnt[blk] = n;
}

// One block per batch: cutoff = largest bin with suffix count >= K
// (superset of the exact sigmoid-top-100 incl. tie groups).
__global__ __launch_bounds__(256) void cut_kernel(const int* __restrict__ bhist,
                                                  int* __restrict__ cut) {
    __shared__ int csum[256];
    __shared__ int s_cut;
    const int b = blockIdx.x;
    const int t = threadIdx.x;

    int h[8]; int chunk = 0;
#pragma unroll
    for (int j = 0; j < 8; ++j) {
        h[j] = bhist[b * NBIN + (t << 3) + j];
        chunk += h[j];
    }
    csum[t] = chunk;
    if (t == 0) s_cut = 0;
    __syncthreads();
    for (int off = 1; off < 256; off <<= 1) {
        int v = (t + off < 256) ? csum[t + off] : 0;
        __syncthreads();
        csum[t] += v;
        __syncthreads();
    }
    if (csum[0] > KK) {
        int running = (t < 255) ? csum[t + 1] : 0;
        if (csum[t] >= KK && running < KK) {   // exactly one thread
            for (int j = 7; j >= 0; --j) {
                running += h[j];
                if (running >= KK) { s_cut = (t << 3) + j; break; }
            }
        }
    }
    __syncthreads();
    if (t == 0) cut[b] = s_cut;
}

// One block per nms record slot: filter records against cut[b] -> per-batch
// survivor list (one returning global atomic per nonempty block, ~300 total).
__global__ __launch_bounds__(256) void filter_kernel(const unsigned* __restrict__ rec,
                                                     const int* __restrict__ pbcnt,
                                                     const int* __restrict__ cut,
                                                     unsigned* __restrict__ surv,
                                                     int* __restrict__ scnt) {
    __shared__ unsigned lbuf[LCAP];
    __shared__ int s_n, s_base;
    const int blk = blockIdx.x;
    const int b = blk / (CC * 2);
    const int t = threadIdx.x;
    if (t == 0) s_n = 0;
    __syncthreads();

    int n = pbcnt[blk]; if (n > BCAP) n = BCAP;
    const unsigned cutb = (unsigned)cut[b];
    const unsigned* __restrict__ rb = rec + (size_t)blk * BCAP;
    for (int i = t; i < n; i += 256) {
        unsigned rv = rb[i];
        if ((rv >> 21) >= cutb) {
            int sl = atomicAdd(&s_n, 1);   // LDS atomic
            if (sl < LCAP) lbuf[sl] = rv & 0x1FFFFFu;
        }
    }
    __syncthreads();
    int m = s_n; if (m > LCAP) m = LCAP;
    if (m == 0) return;
    if (t == 0) s_base = atomicAdd(&scnt[b], m);       // rare, low contention
    __syncthreads();
    const int sb = s_base;
    for (int k = t; k < m; k += 256)
        if (sb + k < SCAP) surv[b * SCAP + sb + k] = lbuf[k];
}

// One block per batch: gather survivors, exact logit -> sigmoid, sort by
// (sigmoid_bits desc, idx asc) == lax.top_k tie semantics, gather + emit.
__global__ __launch_bounds__(256) void topk_kernel(const unsigned* __restrict__ surv,
                                                   const int* __restrict__ scnt,
                                                   const float* __restrict__ hm,
                                                   const float* __restrict__ bbox,
                                                   const float* __restrict__ offs,
                                                   const int* __restrict__ image_id,
                                                   float* __restrict__ out) {
    __shared__ unsigned long long list[SCAP];  // 16 KB
    const int b = blockIdx.x;
    const int t = threadIdx.x;
    int n = scnt[b]; if (n > SCAP) n = SCAP;
    const float* __restrict__ hb = hm + (size_t)b * CC * HWs;

    for (int i = t; i < n; i += 256) {
        unsigned idx = surv[b * SCAP + i];
        float lv = hb[idx];
        float s = 1.0f / (1.0f + expf(-lv));
        list[i] = ((unsigned long long)__float_as_uint(s) << 32) | (unsigned)(~idx);
    }
    int P = 128;
    while (P < n) P <<= 1;
    for (int i = n + t; i < P; i += 256) list[i] = 0ull;
    __syncthreads();

    for (int ksz = 2; ksz <= P; ksz <<= 1) {
        for (int j = ksz >> 1; j > 0; j >>= 1) {
            for (int i = t; i < P; i += 256) {
                int ixj = i ^ j;
                if (ixj > i) {
                    unsigned long long a = list[i], bb2 = list[ixj];
                    bool desc = ((i & ksz) == 0);
                    if (desc ? (a < bb2) : (a > bb2)) { list[i] = bb2; list[ixj] = a; }
                }
            }
            __syncthreads();
        }
    }

    if (t < KK) {
        float s = 0.0f; unsigned idx = 0;
        if (t < n) {
            unsigned long long cv = list[t];
            s = __uint_as_float((unsigned)(cv >> 32));
            idx = ~(unsigned)(cv & 0xFFFFFFFFu) & 0x1FFFFFu;
        }
        unsigned sp = idx & (HWs - 1);
        float cls = (float)(idx >> 14);
        float ysf = (float)(sp >> 7);
        float xsf = (float)(sp & 127);
        const float* __restrict__ ob  = offs + (size_t)b * 2 * HWs;
        const float* __restrict__ bbx = bbox + (size_t)b * 2 * HWs;
        float cx = xsf + ob[sp];
        float cy = ysf + ob[HWs + sp];
        float w = bbx[sp];
        float h = bbx[HWs + sp];
        float* row = out + ((size_t)b * KK + t) * 7;
        row[0] = (float)image_id[b];
        row[1] = (cx - w * 0.5f) * 4.0f;
        row[2] = (cy - h * 0.5f) * 4.0f;
        row[3] = (cx + w * 0.5f) * 4.0f;
        row[4] = (cy + h * 0.5f) * 4.0f;
        row[5] = s;
        row[6] = cls;
    }
}

extern "C" void kernel_launch(void* const* d_in, const int* in_sizes, int n_in,
                              void* d_out, int out_size, void* d_ws, size_t ws_size,
                              hipStream_t stream) {
    const float* hm      = (const float*)d_in[0];
    const float* bbox    = (const float*)d_in[1];
    const float* offset  = (const float*)d_in[2];
    const int*   img_id  = (const int*)d_in[3];
    float* out = (float*)d_out;

    char* ws = (char*)d_ws;
    int*      bhist = (int*)(ws + OFF_BHIST);
    int*      cut   = (int*)(ws + OFF_CUT);
    int*      scnt  = (int*)(ws + OFF_SCNT);
    int*      pbcnt = (int*)(ws + OFF_PBCNT);
    unsigned* surv  = (unsigned*)(ws + OFF_SURV);
    unsigned* rec   = (unsigned*)(ws + OFF_REC);

    zero_kernel<<<32, 256, 0, stream>>>((int4*)bhist, scnt);
    nms_kernel<<<NBLK, 256, 0, stream>>>(hm, rec, pbcnt, bhist);
    cut_kernel<<<BB, 256, 0, stream>>>(bhist, cut);
    filter_kernel<<<NBLK, 256, 0, stream>>>(rec, pbcnt, cut, surv, scnt);
    topk_kernel<<<BB, 256, 0, stream>>>(surv, scnt, hm, bbox, offset, img_id, out);
}

// Round 11
// 62.748 us; speedup vs baseline: 1.2923x; 1.2831x over previous
//
#include <hip/hip_runtime.h>

#define BB 16
#define CC 80
#define HWs 16384           // H*W
#define KK 100
#define NBIN 2048           // histogram bins = okey(logit) >> 21
#define BCAP 2304           // records per plane slot (mean ~1820)
#define SBCAP 128           // survivors per plane slot (mean ~8)

// ws layout (bytes) — identical to the verified R8 layout
#define OFF_BHIST 0                          // 16*2048*4 = 131072
#define OFF_CUT   131072                     // 64
#define OFF_PBCNT 131136                     // 1280*4 = 5120
#define OFF_PSCNT 136256                     // 1280*4 = 5120
#define OFF_REC   141376                     // 1280*2304*4 = 11796480
#define OFF_SURV  11937856                   // 1280*128*4 = 655360 (end ~12.6MB)

__device__ __forceinline__ unsigned okey(float f) {
    unsigned u = __float_as_uint(f);
    return (u & 0x80000000u) ? ~u : (u | 0x80000000u);
}

// zero bhist (128 KB)
__global__ __launch_bounds__(256) void zero_hist_kernel(int4* __restrict__ bhist) {
    int i = blockIdx.x * 256 + threadIdx.x;          // 8192 int4 total
    if (i < BB * NBIN / 4) bhist[i] = make_int4(0, 0, 0, 0);
}

// One block per (b,c) plane. Thread = 4col strip; 2 chunks x 8 rows.
// Per chunk: issue ALL 10 window-row loads, then sched_barrier(0) so the
// scheduler cannot sink them into the compute (VGPR=32 convoy in R8/R10).
// Peaks -> LDS record buffer via LDS atomic (wave-aggregated by compiler);
// hist rebuilt from records once at the end. No returning global atomics.
__global__ __launch_bounds__(256) void nms_kernel(const float* __restrict__ hm,
                                                  unsigned* __restrict__ rec,
                                                  int* __restrict__ pbcnt,
                                                  int* __restrict__ bhist) {
    __shared__ int hist[NBIN];             // 8 KB
    __shared__ unsigned sbuf[BCAP];        // 9 KB
    __shared__ int s_n;
    const int plane = blockIdx.x;          // b*CC + c
    const int b = plane / CC;
    const int c = plane - b * CC;
    const int t = threadIdx.x;
    const int sx = t & 31;                 // 4-wide column strip
    const int x0 = sx << 2;
    const int band0 = (t >> 5) << 4;       // 8 bands x 16 rows
    const float4* __restrict__ src4 =
        reinterpret_cast<const float4*>(hm + (size_t)plane * HWs);

    for (int i = t; i < NBIN; i += 256) hist[i] = 0;
    if (t == 0) s_n = 0;
    __syncthreads();

    auto hmax3 = [&](const float4& a) -> float4 {
        float vm1 = __shfl_up(a.w, 1, 32);
        float vp4 = __shfl_down(a.x, 1, 32);
        if (sx == 0) vm1 = a.x;            // SAME padding (self-dup neutral)
        if (sx == 31) vp4 = a.w;
        float4 h;
        h.x = fmaxf(fmaxf(vm1, a.x), a.y);
        h.y = fmaxf(fmaxf(a.x, a.y), a.z);
        h.z = fmaxf(fmaxf(a.y, a.z), a.w);
        h.w = fmaxf(fmaxf(a.z, a.w), vp4);
        return h;
    };

#pragma unroll
    for (int chunk = 0; chunk < 2; ++chunk) {
        const int y0 = band0 + (chunk << 3);

        // 10 window rows (y0-1 .. y0+8, clamped) — ALL issued before compute
        float4 w[10];
#pragma unroll
        for (int i = 0; i < 10; ++i) {
            int rr = y0 - 1 + i;
            rr = rr < 0 ? 0 : (rr > 127 ? 127 : rr);
            w[i] = src4[(rr << 5) + sx];
        }
        __builtin_amdgcn_sched_barrier(0);   // forbid sinking loads into compute

        float4 hm1 = hmax3(w[0]);
        float4 h0  = hmax3(w[1]);
#pragma unroll
        for (int r = 0; r < 8; ++r) {
            float4 hp1 = hmax3(w[r + 2]);
            float vv[4] = { w[r + 1].x, w[r + 1].y, w[r + 1].z, w[r + 1].w };
            float mm[4] = { fmaxf(fmaxf(hm1.x, h0.x), hp1.x),
                            fmaxf(fmaxf(hm1.y, h0.y), hp1.y),
                            fmaxf(fmaxf(hm1.z, h0.z), hp1.z),
                            fmaxf(fmaxf(hm1.w, h0.w), hp1.w) };
#pragma unroll
            for (int j = 0; j < 4; ++j) {
                if (vv[j] >= mm[j]) {          // peak (max-of-9 incl. self)
                    int sl = atomicAdd(&s_n, 1);       // LDS, wave-aggregated
                    unsigned bin = okey(vv[j]) >> 21;
                    unsigned idx = ((unsigned)c << 14)
                                 | ((unsigned)(y0 + r) << 7) | (unsigned)(x0 + j);
                    if (sl < BCAP) sbuf[sl] = (bin << 21) | idx;
                }
            }
            hm1 = h0; h0 = hp1;
        }
    }
    __syncthreads();
    int n = s_n; if (n > BCAP) n = BCAP;

    // rebuild hist from records (~7/thread), then flush + writeback
    for (int i = t; i < n; i += 256) atomicAdd(&hist[sbuf[i] >> 21], 1);
    __syncthreads();
    for (int i = t; i < NBIN; i += 256) {
        int hv = hist[i];
        if (hv) atomicAdd(&bhist[b * NBIN + i], hv);   // fire-and-forget
    }
    unsigned* __restrict__ rb = rec + (size_t)plane * BCAP;
    for (int i = t; i < n; i += 256) rb[i] = sbuf[i];  // coalesced writeback
    if (t == 0) pbcnt[plane] = n;
}

// One block per batch: cutoff = largest bin with suffix count >= K
// (superset of the exact sigmoid-top-100 incl. tie groups).
__global__ __launch_bounds__(256) void cut_kernel(const int* __restrict__ bhist,
                                                  int* __restrict__ cut) {
    __shared__ int csum[256];
    __shared__ int s_cut;
    const int b = blockIdx.x;
    const int t = threadIdx.x;

    int h[8]; int chunk = 0;
#pragma unroll
    for (int j = 0; j < 8; ++j) {
        h[j] = bhist[b * NBIN + (t << 3) + j];
        chunk += h[j];
    }
    csum[t] = chunk;
    if (t == 0) s_cut = 0;
    __syncthreads();
    for (int off = 1; off < 256; off <<= 1) {
        int v = (t + off < 256) ? csum[t + off] : 0;
        __syncthreads();
        csum[t] += v;
        __syncthreads();
    }
    if (csum[0] > KK) {
        int running = (t < 255) ? csum[t + 1] : 0;
        if (csum[t] >= KK && running < KK) {   // exactly one thread
            for (int j = 7; j >= 0; --j) {
                running += h[j];
                if (running >= KK) { s_cut = (t << 3) + j; break; }
            }
        }
    }
    __syncthreads();
    if (t == 0) cut[b] = s_cut;
}

// One block per plane slot: filter records against cut[b] -> survivor slot
// (LDS-atomic compaction only; plain stores, no returning global atomics).
__global__ __launch_bounds__(256) void filter_kernel(const unsigned* __restrict__ rec,
                                                     const int* __restrict__ pbcnt,
                                                     const int* __restrict__ cut,
                                                     unsigned* __restrict__ surv,
                                                     int* __restrict__ pscnt) {
    __shared__ int s_n;
    const int bx = blockIdx.x;             // b*CC + c
    const int b = bx / CC;
    const int t = threadIdx.x;
    if (t == 0) s_n = 0;
    __syncthreads();

    int n = pbcnt[bx]; if (n > BCAP) n = BCAP;
    const int cutb = cut[b];
    const unsigned* __restrict__ rb = rec + (size_t)bx * BCAP;
    unsigned* __restrict__ sb = surv + (size_t)bx * SBCAP;
    for (int i = t; i < n; i += 256) {
        unsigned rv = rb[i];
        if ((int)(rv >> 21) >= cutb) {
            int sl = atomicAdd(&s_n, 1);   // LDS atomic: cheap
            if (sl < SBCAP) sb[sl] = rv & 0x1FFFFFu;
        }
    }
    __syncthreads();
    if (t == 0) pscnt[bx] = s_n > SBCAP ? SBCAP : s_n;
}

// One block per batch: gather survivors, exact logit -> sigmoid, sort by
// (sigmoid_bits desc, idx asc) == lax.top_k tie semantics, gather + emit.
__global__ __launch_bounds__(256) void topk_kernel(const unsigned* __restrict__ surv,
                                                   const int* __restrict__ pscnt,
                                                   const float* __restrict__ hm,
                                                   const float* __restrict__ bbox,
                                                   const float* __restrict__ offs,
                                                   const int* __restrict__ image_id,
                                                   float* __restrict__ out) {
    __shared__ int lcnt[CC];
    __shared__ unsigned uidx[2048];            // 8 KB
    __shared__ unsigned long long list[2048];  // 16 KB
    __shared__ int s_n;
    const int b = blockIdx.x;
    const int t = threadIdx.x;
    const float* __restrict__ hb = hm + (size_t)b * CC * HWs;

    if (t < CC) lcnt[t] = pscnt[b * CC + t];
    if (t == 0) s_n = 0;
    __syncthreads();

    for (int s = t; s < CC; s += 256) {
        int cs = lcnt[s]; if (cs > SBCAP) cs = SBCAP;
        if (cs) {
            int base = atomicAdd(&s_n, cs);
            const unsigned* __restrict__ sb = surv + ((size_t)b * CC + s) * SBCAP;
            for (int k = 0; k < cs; ++k)
                if (base + k < 2048) uidx[base + k] = sb[k];
        }
    }
    __syncthreads();
    int n = s_n; if (n > 2048) n = 2048;

    for (int i = t; i < n; i += 256) {
        unsigned idx = uidx[i];
        float lv = hb[idx];
        float s = 1.0f / (1.0f + expf(-lv));
        list[i] = ((unsigned long long)__float_as_uint(s) << 32) | (unsigned)(~idx);
    }
    int P = 128;
    while (P < n) P <<= 1;
    for (int i = n + t; i < P; i += 256) list[i] = 0ull;
    __syncthreads();

    for (int ksz = 2; ksz <= P; ksz <<= 1) {
        for (int j = ksz >> 1; j > 0; j >>= 1) {
            for (int i = t; i < P; i += 256) {
                int ixj = i ^ j;
                if (ixj > i) {
                    unsigned long long a = list[i], bb2 = list[ixj];
                    bool desc = ((i & ksz) == 0);
                    if (desc ? (a < bb2) : (a > bb2)) { list[i] = bb2; list[ixj] = a; }
                }
            }
            __syncthreads();
        }
    }

    if (t < KK) {
        float s = 0.0f; unsigned idx = 0;
        if (t < n) {
            unsigned long long cv = list[t];
            s = __uint_as_float((unsigned)(cv >> 32));
            idx = ~(unsigned)(cv & 0xFFFFFFFFu) & 0x1FFFFFu;
        }
        unsigned sp = idx & (HWs - 1);
        float cls = (float)(idx >> 14);
        float ysf = (float)(sp >> 7);
        float xsf = (float)(sp & 127);
        const float* __restrict__ ob  = offs + (size_t)b * 2 * HWs;
        const float* __restrict__ bbx = bbox + (size_t)b * 2 * HWs;
        float cx = xsf + ob[sp];
        float cy = ysf + ob[HWs + sp];
        float w = bbx[sp];
        float h = bbx[HWs + sp];
        float* row = out + ((size_t)b * KK + t) * 7;
        row[0] = (float)image_id[b];
        row[1] = (cx - w * 0.5f) * 4.0f;
        row[2] = (cy - h * 0.5f) * 4.0f;
        row[3] = (cx + w * 0.5f) * 4.0f;
        row[4] = (cy + h * 0.5f) * 4.0f;
        row[5] = s;
        row[6] = cls;
    }
}

extern "C" void kernel_launch(void* const* d_in, const int* in_sizes, int n_in,
                              void* d_out, int out_size, void* d_ws, size_t ws_size,
                              hipStream_t stream) {
    const float* hm      = (const float*)d_in[0];
    const float* bbox    = (const float*)d_in[1];
    const float* offset  = (const float*)d_in[2];
    const int*   img_id  = (const int*)d_in[3];
    float* out = (float*)d_out;

    char* ws = (char*)d_ws;
    int*      bhist = (int*)(ws + OFF_BHIST);
    int*      cut   = (int*)(ws + OFF_CUT);
    int*      pbcnt = (int*)(ws + OFF_PBCNT);
    int*      pscnt = (int*)(ws + OFF_PSCNT);
    unsigned* rec   = (unsigned*)(ws + OFF_REC);
    unsigned* surv  = (unsigned*)(ws + OFF_SURV);

    zero_hist_kernel<<<32, 256, 0, stream>>>((int4*)bhist);
    nms_kernel<<<BB * CC, 256, 0, stream>>>(hm, rec, pbcnt, bhist);
    cut_kernel<<<BB, 256, 0, stream>>>(bhist, cut);
    filter_kernel<<<BB * CC, 256, 0, stream>>>(rec, pbcnt, cut, surv, pscnt);
    topk_kernel<<<BB, 256, 0, stream>>>(surv, pscnt, hm, bbox, offset, img_id, out);
}

// Round 12
// 60.342 us; speedup vs baseline: 1.3438x; 1.0399x over previous
//
#include <hip/hip_runtime.h>

#define BB 16
#define CC 80
#define HWs 16384           // H*W
#define KK 100
#define NBIN 2048           // histogram bins = okey(logit) >> 21
#define NBLK (BB * CC * 2)  // 2560 half-plane blocks
#define NSLOT 160           // half-plane slots per batch = CC*2
#define BCAP 1152           // records per half-plane slot (mean ~910, +27%)
#define SBCAP 64            // survivors per half-plane slot (mean ~4)

// ws layout (bytes)
#define OFF_BHIST 0                          // 16*2048*4 = 131072
#define OFF_PBCNT 131072                     // 2560*4 = 10240
#define OFF_PSCNT 141312                     // 2560*4 = 10240
#define OFF_SURV  151552                     // 2560*64*4 = 655360
#define OFF_REC   806912                     // 2560*1152*4 = 11796480 (end ~12.6MB)

__device__ __forceinline__ unsigned okey(float f) {
    unsigned u = __float_as_uint(f);
    return (u & 0x80000000u) ? ~u : (u | 0x80000000u);
}

// zero bhist (128 KB)
__global__ __launch_bounds__(256) void zero_hist_kernel(int4* __restrict__ bhist) {
    int i = blockIdx.x * 256 + threadIdx.x;          // 8192 int4 total
    if (i < BB * NBIN / 4) bhist[i] = make_int4(0, 0, 0, 0);
}

// One block per half-plane (2560 blocks, 12.6 KB LDS -> 8 blocks/CU = 32
// waves = 100% occupancy). Thread = 4col x 8row strip, 10 window-row loads.
// Peaks -> LDS record buffer via LDS atomic; hist rebuilt from records at
// the end; writeback to block-owned slot. No returning global atomics.
__global__ __launch_bounds__(256) void nms_kernel(const float* __restrict__ hm,
                                                  unsigned* __restrict__ rec,
                                                  int* __restrict__ pbcnt,
                                                  int* __restrict__ bhist) {
    __shared__ int hist[NBIN];             // 8 KB
    __shared__ unsigned sbuf[BCAP];        // 4.5 KB
    __shared__ int s_n;
    const int blk = blockIdx.x;            // plane*2 + half
    const int plane = blk >> 1;
    const int half = blk & 1;
    const int b = plane / CC;
    const int c = plane - b * CC;
    const int t = threadIdx.x;
    const int sx = t & 31;                 // 4-wide column strip
    const int x0 = sx << 2;
    const int y0 = (half << 6) + ((t >> 5) << 3);    // 8 bands x 8 rows
    const float4* __restrict__ src4 =
        reinterpret_cast<const float4*>(hm + (size_t)plane * HWs);

    for (int i = t; i < NBIN; i += 256) hist[i] = 0;
    if (t == 0) s_n = 0;
    __syncthreads();

    // 10 window rows (y0-1 .. y0+8, clamped) issued before compute
    float4 w[10];
#pragma unroll
    for (int i = 0; i < 10; ++i) {
        int rr = y0 - 1 + i;
        rr = rr < 0 ? 0 : (rr > 127 ? 127 : rr);
        w[i] = src4[(rr << 5) + sx];
    }
    __builtin_amdgcn_sched_barrier(0);

    auto hmax3 = [&](const float4& a) -> float4 {
        float vm1 = __shfl_up(a.w, 1, 32);
        float vp4 = __shfl_down(a.x, 1, 32);
        if (sx == 0) vm1 = a.x;            // SAME padding (self-dup neutral)
        if (sx == 31) vp4 = a.w;
        float4 h;
        h.x = fmaxf(fmaxf(vm1, a.x), a.y);
        h.y = fmaxf(fmaxf(a.x, a.y), a.z);
        h.z = fmaxf(fmaxf(a.y, a.z), a.w);
        h.w = fmaxf(fmaxf(a.z, a.w), vp4);
        return h;
    };

    float4 hm1 = hmax3(w[0]);
    float4 h0  = hmax3(w[1]);
#pragma unroll
    for (int r = 0; r < 8; ++r) {
        float4 hp1 = hmax3(w[r + 2]);
        float vv[4] = { w[r + 1].x, w[r + 1].y, w[r + 1].z, w[r + 1].w };
        float mm[4] = { fmaxf(fmaxf(hm1.x, h0.x), hp1.x),
                        fmaxf(fmaxf(hm1.y, h0.y), hp1.y),
                        fmaxf(fmaxf(hm1.z, h0.z), hp1.z),
                        fmaxf(fmaxf(hm1.w, h0.w), hp1.w) };
#pragma unroll
        for (int j = 0; j < 4; ++j) {
            if (vv[j] >= mm[j]) {          // peak (max-of-9 incl. self)
                int sl = atomicAdd(&s_n, 1);           // LDS atomic
                unsigned bin = okey(vv[j]) >> 21;
                unsigned idx = ((unsigned)c << 14)
                             | ((unsigned)(y0 + r) << 7) | (unsigned)(x0 + j);
                if (sl < BCAP) sbuf[sl] = (bin << 21) | idx;
            }
        }
        hm1 = h0; h0 = hp1;
    }
    __syncthreads();
    int n = s_n; if (n > BCAP) n = BCAP;

    // rebuild hist from records (~4/thread), flush + writeback
    for (int i = t; i < n; i += 256) atomicAdd(&hist[sbuf[i] >> 21], 1);
    __syncthreads();
    for (int i = t; i < NBIN; i += 256) {
        int hv = hist[i];
        if (hv) atomicAdd(&bhist[b * NBIN + i], hv);   // fire-and-forget
    }
    unsigned* __restrict__ rb = rec + (size_t)blk * BCAP;
    for (int i = t; i < n; i += 256) rb[i] = sbuf[i];  // coalesced writeback
    if (t == 0) pbcnt[blk] = n;
}

// One block per half-plane slot: compute cut[b] inline (verified R5 logic:
// largest bin with suffix >= K — superset of exact top-100 incl. ties),
// then filter own record slot -> deterministic survivor slot.
__global__ __launch_bounds__(256) void filter_kernel(const unsigned* __restrict__ rec,
                                                     const int* __restrict__ pbcnt,
                                                     const int* __restrict__ bhist,
                                                     unsigned* __restrict__ surv,
                                                     int* __restrict__ pscnt) {
    __shared__ int csum[256];
    __shared__ int s_cut, s_n;
    const int blk = blockIdx.x;            // b*NSLOT + slot
    const int b = blk / NSLOT;
    const int t = threadIdx.x;

    // inline cut computation from global bhist
    int h[8]; int chunk = 0;
#pragma unroll
    for (int j = 0; j < 8; ++j) {
        h[j] = bhist[b * NBIN + (t << 3) + j];
        chunk += h[j];
    }
    csum[t] = chunk;
    if (t == 0) { s_cut = 0; s_n = 0; }
    __syncthreads();
    for (int off = 1; off < 256; off <<= 1) {
        int v = (t + off < 256) ? csum[t + off] : 0;
        __syncthreads();
        csum[t] += v;
        __syncthreads();
    }
    if (csum[0] > KK) {
        int running = (t < 255) ? csum[t + 1] : 0;
        if (csum[t] >= KK && running < KK) {   // exactly one thread
            for (int j = 7; j >= 0; --j) {
                running += h[j];
                if (running >= KK) { s_cut = (t << 3) + j; break; }
            }
        }
    }
    __syncthreads();
    const unsigned cutb = (unsigned)s_cut;

    int n = pbcnt[blk]; if (n > BCAP) n = BCAP;
    const unsigned* __restrict__ rb = rec + (size_t)blk * BCAP;
    unsigned* __restrict__ sb = surv + (size_t)blk * SBCAP;
    for (int i = t; i < n; i += 256) {
        unsigned rv = rb[i];
        if ((rv >> 21) >= cutb) {
            int sl = atomicAdd(&s_n, 1);   // LDS atomic: cheap
            if (sl < SBCAP) sb[sl] = rv & 0x1FFFFFu;
        }
    }
    __syncthreads();
    if (t == 0) pscnt[blk] = s_n > SBCAP ? SBCAP : s_n;
}

// One block per batch: gather survivors, exact logit -> sigmoid, sort by
// (sigmoid_bits desc, idx asc) == lax.top_k tie semantics, gather + emit.
__global__ __launch_bounds__(256) void topk_kernel(const unsigned* __restrict__ surv,
                                                   const int* __restrict__ pscnt,
                                                   const float* __restrict__ hm,
                                                   const float* __restrict__ bbox,
                                                   const float* __restrict__ offs,
                                                   const int* __restrict__ image_id,
                                                   float* __restrict__ out) {
    __shared__ int lcnt[NSLOT];
    __shared__ unsigned uidx[2048];            // 8 KB
    __shared__ unsigned long long list[2048];  // 16 KB
    __shared__ int s_n;
    const int b = blockIdx.x;
    const int t = threadIdx.x;
    const float* __restrict__ hb = hm + (size_t)b * CC * HWs;

    if (t < NSLOT) lcnt[t] = pscnt[b * NSLOT + t];
    if (t == 0) s_n = 0;
    __syncthreads();

    for (int s = t; s < NSLOT; s += 256) {
        int cs = lcnt[s]; if (cs > SBCAP) cs = SBCAP;
        if (cs) {
            int base = atomicAdd(&s_n, cs);
            const unsigned* __restrict__ sb = surv + ((size_t)b * NSLOT + s) * SBCAP;
            for (int k = 0; k < cs; ++k)
                if (base + k < 2048) uidx[base + k] = sb[k];
        }
    }
    __syncthreads();
    int n = s_n; if (n > 2048) n = 2048;

    for (int i = t; i < n; i += 256) {
        unsigned idx = uidx[i];
        float lv = hb[idx];
        float s = 1.0f / (1.0f + expf(-lv));
        list[i] = ((unsigned long long)__float_as_uint(s) << 32) | (unsigned)(~idx);
    }
    int P = 128;
    while (P < n) P <<= 1;
    for (int i = n + t; i < P; i += 256) list[i] = 0ull;
    __syncthreads();

    for (int ksz = 2; ksz <= P; ksz <<= 1) {
        for (int j = ksz >> 1; j > 0; j >>= 1) {
            for (int i = t; i < P; i += 256) {
                int ixj = i ^ j;
                if (ixj > i) {
                    unsigned long long a = list[i], bb2 = list[ixj];
                    bool desc = ((i & ksz) == 0);
                    if (desc ? (a < bb2) : (a > bb2)) { list[i] = bb2; list[ixj] = a; }
                }
            }
            __syncthreads();
        }
    }

    if (t < KK) {
        float s = 0.0f; unsigned idx = 0;
        if (t < n) {
            unsigned long long cv = list[t];
            s = __uint_as_float((unsigned)(cv >> 32));
            idx = ~(unsigned)(cv & 0xFFFFFFFFu) & 0x1FFFFFu;
        }
        unsigned sp = idx & (HWs - 1);
        float cls = (float)(idx >> 14);
        float ysf = (float)(sp >> 7);
        float xsf = (float)(sp & 127);
        const float* __restrict__ ob  = offs + (size_t)b * 2 * HWs;
        const float* __restrict__ bbx = bbox + (size_t)b * 2 * HWs;
        float cx = xsf + ob[sp];
        float cy = ysf + ob[HWs + sp];
        float w = bbx[sp];
        float h = bbx[HWs + sp];
        float* row = out + ((size_t)b * KK + t) * 7;
        row[0] = (float)image_id[b];
        row[1] = (cx - w * 0.5f) * 4.0f;
        row[2] = (cy - h * 0.5f) * 4.0f;
        row[3] = (cx + w * 0.5f) * 4.0f;
        row[4] = (cy + h * 0.5f) * 4.0f;
        row[5] = s;
        row[6] = cls;
    }
}

extern "C" void kernel_launch(void* const* d_in, const int* in_sizes, int n_in,
                              void* d_out, int out_size, void* d_ws, size_t ws_size,
                              hipStream_t stream) {
    const float* hm      = (const float*)d_in[0];
    const float* bbox    = (const float*)d_in[1];
    const float* offset  = (const float*)d_in[2];
    const int*   img_id  = (const int*)d_in[3];
    float* out = (float*)d_out;

    char* ws = (char*)d_ws;
    int*      bhist = (int*)(ws + OFF_BHIST);
    int*      pbcnt = (int*)(ws + OFF_PBCNT);
    int*      pscnt = (int*)(ws + OFF_PSCNT);
    unsigned* surv  = (unsigned*)(ws + OFF_SURV);
    unsigned* rec   = (unsigned*)(ws + OFF_REC);

    zero_hist_kernel<<<32, 256, 0, stream>>>((int4*)bhist);
    nms_kernel<<<NBLK, 256, 0, stream>>>(hm, rec, pbcnt, bhist);
    filter_kernel<<<NBLK, 256, 0, stream>>>(rec, pbcnt, bhist, surv, pscnt);
    topk_kernel<<<BB, 256, 0, stream>>>(surv, pscnt, hm, bbox, offset, img_id, out);
}